// Round 1
// baseline (2860.109 us; speedup 1.0000x reference)
//
#include <hip/hip_runtime.h>
#include <cstdint>
#include <cstddef>

// ---------------- problem constants ----------------
#define B_   64
#define P_   196
#define E_   2048
#define A_   512
#define D_   512
#define EMB_ 512
#define V_   10000
#define T_   40
// concatenated h-GEMM column space: [dec_att(512) | f_beta(2048) | W_hh(2048) | fc(10000)]
#define NCAT  14608
#define NCATP 14656   // padded to 229*64

typedef unsigned short u16;
typedef __attribute__((ext_vector_type(8))) short bf16x8;  // 8 bf16 = 4 VGPRs
typedef __attribute__((ext_vector_type(4))) float f32x4;

__device__ __forceinline__ f32x4 mfma_bf16(bf16x8 a, bf16x8 b, f32x4 c) {
  return __builtin_amdgcn_mfma_f32_16x16x32_bf16(a, b, c, 0, 0, 0);
}
__device__ __forceinline__ u16 f2b(float f) {            // RNE f32->bf16 (no NaN in data)
  unsigned u = __builtin_bit_cast(unsigned, f);
  u += 0x7fffu + ((u >> 16) & 1u);
  return (u16)(u >> 16);
}
__device__ __forceinline__ float b2f(u16 s) {
  unsigned u = ((unsigned)s) << 16;
  return __builtin_bit_cast(float, u);
}
__device__ __forceinline__ float sigf(float x) { return 1.0f / (1.0f + __expf(-x)); }

// ---------------- prolog kernels ----------------
__global__ __launch_bounds__(256) void k_cvt_bf16(const float* __restrict__ s,
                                                  u16* __restrict__ d, int n4) {
  int i = blockIdx.x * 256 + threadIdx.x;
  if (i >= n4) return;
  float4 v = reinterpret_cast<const float4*>(s)[i];
  u16* o = d + (size_t)i * 4;
  o[0] = f2b(v.x); o[1] = f2b(v.y); o[2] = f2b(v.z); o[3] = f2b(v.w);
}

__global__ __launch_bounds__(256) void k_mean(const float* __restrict__ enc,
                                              float* __restrict__ meanE) {
  int i = blockIdx.x * 256 + threadIdx.x;   // 64*2048
  int b = i >> 11, e = i & 2047;
  const float* p = enc + (size_t)b * P_ * E_ + e;
  float s = 0.f;
  for (int pp = 0; pp < P_; ++pp) s += p[(size_t)pp * E_];
  meanE[i] = s * (1.0f / (float)P_);
}

// dst[n*dstStride + k] = src[k*srcStride + n]  (fp32 -> bf16), LDS-tiled
__global__ __launch_bounds__(256) void k_transpose_bf16(
    const float* __restrict__ src, int srcStride,
    u16* __restrict__ dst, int dstStride, int N, int K) {
  __shared__ float t[32][33];
  int kt = blockIdx.x * 32, nt = blockIdx.y * 32;
  int tx = threadIdx.x & 31, ty = threadIdx.x >> 5;
  #pragma unroll
  for (int i = 0; i < 4; ++i) {
    int k = kt + ty + i * 8, n = nt + tx;
    t[ty + i * 8][tx] = (k < K && n < N) ? src[(size_t)k * srcStride + n] : 0.0f;
  }
  __syncthreads();
  #pragma unroll
  for (int i = 0; i < 4; ++i) {
    int n = nt + ty + i * 8, k = kt + tx;
    if (n < N && k < K) dst[(size_t)n * dstStride + k] = f2b(t[tx][ty + i * 8]);
  }
}

__global__ __launch_bounds__(256) void k_init_hc(
    const float* __restrict__ meanE,
    const float* __restrict__ Wh, const float* __restrict__ bh,
    const float* __restrict__ Wc, const float* __restrict__ bc,
    u16* __restrict__ h_bf, float* __restrict__ c_f) {
  int i = blockIdx.x * 256 + threadIdx.x;   // 64*512
  int b = i >> 9, n = i & 511;
  const float* m = meanE + (size_t)b * E_;
  float ah = 0.f, ac = 0.f;
  for (int k = 0; k < E_; ++k) {
    float mv = m[k];
    ah += mv * Wh[(size_t)k * D_ + n];
    ac += mv * Wc[(size_t)k * D_ + n];
  }
  h_bf[i] = f2b(ah + bh[n]);
  c_f[i]  = ac + bc[n];
}

__global__ __launch_bounds__(256) void k_emb(const int* __restrict__ captions,
                                             const float* __restrict__ embedding,
                                             u16* __restrict__ embs) {
  int i = blockIdx.x * 256 + threadIdx.x;   // (T*B)*EMB, row m = t*64+b
  int m = i >> 9, k = i & 511;
  int t = m >> 6, b = m & 63;
  int cap = captions[b * T_ + t];
  embs[i] = f2b(embedding[(size_t)cap * EMB_ + k]);
}

__global__ __launch_bounds__(256) void k_bsum(const float* __restrict__ a,
                                              const float* __restrict__ b,
                                              float* __restrict__ o) {
  int i = blockIdx.x * 256 + threadIdx.x;   // 2048
  o[i] = a[i] + b[i];
}

// ---------------- generic MFMA GEMM:  out[M][N] = A[M][K] @ Bt[N][K]^T + bias ----------------
// block = 64x64 tile, 4 waves (wave w owns rows 16w..16w+15), no LDS (round-0 simplicity)
template <bool BF16OUT>
__global__ __launch_bounds__(256) void k_gemm_bt(
    const u16* __restrict__ Am, const u16* __restrict__ Bt,
    const float* __restrict__ bias, void* __restrict__ outp, int K, int N) {
  int m0 = blockIdx.x * 64, n0 = blockIdx.y * 64;
  int w = threadIdx.x >> 6, lane = threadIdx.x & 63;
  int lr = lane & 15, lg = lane >> 4;
  const u16* ap = Am + (size_t)(m0 + 16 * w + lr) * K + lg * 8;
  const u16* bp = Bt + (size_t)(n0 + lr) * K + lg * 8;
  f32x4 acc0 = {}, acc1 = {}, acc2 = {}, acc3 = {};
  for (int k = 0; k < K; k += 32) {
    bf16x8 a  = *reinterpret_cast<const bf16x8*>(ap + k);
    bf16x8 b0 = *reinterpret_cast<const bf16x8*>(bp + k);
    bf16x8 b1 = *reinterpret_cast<const bf16x8*>(bp + (size_t)16 * K + k);
    bf16x8 b2 = *reinterpret_cast<const bf16x8*>(bp + (size_t)32 * K + k);
    bf16x8 b3 = *reinterpret_cast<const bf16x8*>(bp + (size_t)48 * K + k);
    acc0 = mfma_bf16(a, b0, acc0);
    acc1 = mfma_bf16(a, b1, acc1);
    acc2 = mfma_bf16(a, b2, acc2);
    acc3 = mfma_bf16(a, b3, acc3);
  }
  int row = m0 + 16 * w + 4 * lg;
  f32x4 accs[4] = {acc0, acc1, acc2, acc3};
  #pragma unroll
  for (int ns = 0; ns < 4; ++ns) {
    int col = n0 + 16 * ns + lr;
    float bv = bias[col];
    #pragma unroll
    for (int r = 0; r < 4; ++r) {
      float v = accs[ns][r] + bv;
      if (BF16OUT) ((u16*)outp)[(size_t)(row + r) * N + col] = f2b(v);
      else         ((float*)outp)[(size_t)(row + r) * N + col] = v;
    }
  }
}

// ---------------- per-step kernels ----------------
// A: all h-dependent GEMMs fused over concatenated N: att2 | sigmoid-gate | hWhh(+embW) | preds(prev)
__global__ __launch_bounds__(256) void k_stepA(
    const u16* __restrict__ h_bf, const u16* __restrict__ catW,
    const float* __restrict__ dec_b, const float* __restrict__ fbeta_b,
    const float* __restrict__ fc_b, const float* __restrict__ embW_t,
    float* __restrict__ att2, float* __restrict__ gate,
    float* __restrict__ gates, float* __restrict__ preds, int wp) {
  int n0 = blockIdx.x * 64;
  int w = threadIdx.x >> 6, lane = threadIdx.x & 63;
  int lr = lane & 15, lg = lane >> 4;
  const u16* ap = h_bf + (size_t)(16 * w + lr) * 512 + lg * 8;
  const u16* bp = catW + (size_t)(n0 + lr) * 512 + lg * 8;
  f32x4 acc0 = {}, acc1 = {}, acc2 = {}, acc3 = {};
  for (int k = 0; k < 512; k += 32) {
    bf16x8 a  = *reinterpret_cast<const bf16x8*>(ap + k);
    bf16x8 b0 = *reinterpret_cast<const bf16x8*>(bp + k);
    bf16x8 b1 = *reinterpret_cast<const bf16x8*>(bp + (size_t)16 * 512 + k);
    bf16x8 b2 = *reinterpret_cast<const bf16x8*>(bp + (size_t)32 * 512 + k);
    bf16x8 b3 = *reinterpret_cast<const bf16x8*>(bp + (size_t)48 * 512 + k);
    acc0 = mfma_bf16(a, b0, acc0);
    acc1 = mfma_bf16(a, b1, acc1);
    acc2 = mfma_bf16(a, b2, acc2);
    acc3 = mfma_bf16(a, b3, acc3);
  }
  int brow = 16 * w + 4 * lg;
  f32x4 accs[4] = {acc0, acc1, acc2, acc3};
  #pragma unroll
  for (int ns = 0; ns < 4; ++ns) {
    int n = n0 + 16 * ns + lr;
    #pragma unroll
    for (int r = 0; r < 4; ++r) {
      int b = brow + r;
      float v = accs[ns][r];
      if (n < 512) {
        att2[b * 512 + n] = v + dec_b[n];
      } else if (n < 2560) {
        int j = n - 512;
        gate[b * 2048 + j] = sigf(v + fbeta_b[j]);
      } else if (n < 4608) {
        int j = n - 2560;
        gates[b * 2048 + j] = v + embW_t[b * 2048 + j];  // embW already holds b_ih+b_hh
      } else if (n < 14608) {
        int j = n - 4608;
        if (wp) preds[(size_t)b * (T_ * V_) + j] = v + fc_b[j];
      }
    }
  }
}

// B: e[b,p] = relu(att1[b,p,:] + att2[b,:]) . full_att_W + full_att_b   (one wave per (b,p))
__global__ __launch_bounds__(256) void k_stepB(
    const u16* __restrict__ att1, const float* __restrict__ att2,
    const float* __restrict__ wf, const float* __restrict__ bf_,
    float* __restrict__ e) {
  int unit = blockIdx.x * 4 + (threadIdx.x >> 6);   // (b*196+p) in [0,12544)
  int lane = threadIdx.x & 63;
  int b = unit / 196;
  const u16*  a1  = att1 + (size_t)unit * 512 + lane * 8;
  const float* a2 = att2 + b * 512 + lane * 8;
  const float* wv = wf + lane * 8;
  float s = 0.f;
  #pragma unroll
  for (int j = 0; j < 8; ++j) {
    float x = b2f(a1[j]) + a2[j];
    s += fmaxf(x, 0.f) * wv[j];
  }
  #pragma unroll
  for (int off = 32; off > 0; off >>= 1) s += __shfl_xor(s, off);
  if (lane == 0) e[unit] = s + bf_[0];
}

// D: softmax(e) (redundant per block) + alphas out + context + gate*context -> bf16
__global__ __launch_bounds__(256) void k_stepD(
    const float* __restrict__ e, const u16* __restrict__ enc_bf,
    const float* __restrict__ gate, float* __restrict__ alphas,
    u16* __restrict__ gctx) {
  __shared__ float sal[P_];
  __shared__ float red[256];
  int b = blockIdx.x >> 3, ch = blockIdx.x & 7;
  int tid = threadIdx.x;
  float ev = (tid < P_) ? e[b * P_ + tid] : -1e30f;
  red[tid] = ev; __syncthreads();
  for (int s = 128; s > 0; s >>= 1) {
    if (tid < s) red[tid] = fmaxf(red[tid], red[tid + s]);
    __syncthreads();
  }
  float mx = red[0]; __syncthreads();
  float ex = (tid < P_) ? __expf(ev - mx) : 0.f;
  red[tid] = ex; __syncthreads();
  for (int s = 128; s > 0; s >>= 1) {
    if (tid < s) red[tid] += red[tid + s];
    __syncthreads();
  }
  float inv = 1.0f / red[0];
  if (tid < P_) {
    float al = ex * inv;
    sal[tid] = al;
    if (ch == 0) alphas[(size_t)b * (T_ * P_) + tid] = al;
  }
  __syncthreads();
  int eidx = ch * 256 + tid;
  const u16* ep = enc_bf + (size_t)b * P_ * E_ + eidx;
  float acc = 0.f;
  #pragma unroll 4
  for (int p = 0; p < P_; ++p) acc += sal[p] * b2f(ep[(size_t)p * E_]);
  gctx[b * E_ + eidx] = f2b(acc * gate[b * E_ + eidx]);
}

// E1: gates += (gate*context) @ W_ih[512:,:]   (split-K=8, atomicAdd)
__global__ __launch_bounds__(256) void k_stepE1(
    const u16* __restrict__ gctx, const u16* __restrict__ Wt,
    float* __restrict__ gates) {
  int n0 = (blockIdx.x & 31) * 64;
  int k0 = (blockIdx.x >> 5) * 256;
  int w = threadIdx.x >> 6, lane = threadIdx.x & 63;
  int lr = lane & 15, lg = lane >> 4;
  const u16* ap = gctx + (size_t)(16 * w + lr) * 2048 + lg * 8 + k0;
  const u16* bp = Wt + (size_t)(n0 + lr) * 2048 + lg * 8 + k0;
  f32x4 acc0 = {}, acc1 = {}, acc2 = {}, acc3 = {};
  for (int k = 0; k < 256; k += 32) {
    bf16x8 a  = *reinterpret_cast<const bf16x8*>(ap + k);
    bf16x8 b0 = *reinterpret_cast<const bf16x8*>(bp + k);
    bf16x8 b1 = *reinterpret_cast<const bf16x8*>(bp + (size_t)16 * 2048 + k);
    bf16x8 b2 = *reinterpret_cast<const bf16x8*>(bp + (size_t)32 * 2048 + k);
    bf16x8 b3 = *reinterpret_cast<const bf16x8*>(bp + (size_t)48 * 2048 + k);
    acc0 = mfma_bf16(a, b0, acc0);
    acc1 = mfma_bf16(a, b1, acc1);
    acc2 = mfma_bf16(a, b2, acc2);
    acc3 = mfma_bf16(a, b3, acc3);
  }
  int brow = 16 * w + 4 * lg;
  f32x4 accs[4] = {acc0, acc1, acc2, acc3};
  #pragma unroll
  for (int ns = 0; ns < 4; ++ns) {
    int n = n0 + 16 * ns + lr;
    #pragma unroll
    for (int r = 0; r < 4; ++r)
      atomicAdd(&gates[(brow + r) * 2048 + n], accs[ns][r]);
  }
}

// E2: LSTM cell elementwise
__global__ __launch_bounds__(256) void k_stepE2(
    const float* __restrict__ gates, float* __restrict__ c, u16* __restrict__ h_bf) {
  int i = blockIdx.x * 256 + threadIdx.x;   // 64*512
  int b = i >> 9, d = i & 511;
  const float* g = gates + (size_t)b * 2048;
  float gi = g[d], gf = g[d + 512], gg = g[d + 1024], go = g[d + 1536];
  float cn = sigf(gf) * c[i] + sigf(gi) * tanhf(gg);
  float hn = sigf(go) * tanhf(cn);
  c[i] = cn;
  h_bf[i] = f2b(hn);
}

// ---------------- host ----------------
extern "C" void kernel_launch(void* const* d_in, const int* in_sizes, int n_in,
                              void* d_out, int out_size, void* d_ws, size_t ws_size,
                              hipStream_t stream) {
  (void)in_sizes; (void)n_in; (void)out_size;
  const float* enc        = (const float*)d_in[0];
  const int*   captions   = (const int*)d_in[1];
  const float* enc_att_W  = (const float*)d_in[3];
  const float* enc_att_b  = (const float*)d_in[4];
  const float* dec_att_W  = (const float*)d_in[5];
  const float* dec_att_b  = (const float*)d_in[6];
  const float* full_att_W = (const float*)d_in[7];
  const float* full_att_b = (const float*)d_in[8];
  const float* embedding  = (const float*)d_in[9];
  const float* W_ih       = (const float*)d_in[10];
  const float* b_ih       = (const float*)d_in[11];
  const float* W_hh       = (const float*)d_in[12];
  const float* b_hh       = (const float*)d_in[13];
  const float* init_h_W   = (const float*)d_in[14];
  const float* init_h_b   = (const float*)d_in[15];
  const float* init_c_W   = (const float*)d_in[16];
  const float* init_c_b   = (const float*)d_in[17];
  const float* fc_W       = (const float*)d_in[18];
  const float* fc_b       = (const float*)d_in[19];
  const float* f_beta_W   = (const float*)d_in[20];
  const float* f_beta_b   = (const float*)d_in[21];

  float* preds_out  = (float*)d_out;                          // [64][40][10000]
  float* alphas_out = (float*)d_out + (size_t)B_ * T_ * V_;   // [64][40][196]

  char* w = (char*)d_ws;
  auto alloc = [&](size_t bytes) -> char* {
    char* p = w; w += (bytes + 255) & ~(size_t)255; return p;
  };
  u16*   enc_bf   = (u16*)  alloc((size_t)B_ * P_ * E_ * 2);       // 51.4 MB
  u16*   att1_bf  = (u16*)  alloc((size_t)B_ * P_ * A_ * 2);       // 12.8 MB
  u16*   catW     = (u16*)  alloc((size_t)NCATP * 512 * 2);        // 15.0 MB
  u16*   encattWT = (u16*)  alloc((size_t)A_ * E_ * 2);            //  2.1 MB
  u16*   WihembT  = (u16*)  alloc((size_t)2048 * 512 * 2);         //  2.1 MB
  u16*   Wih2T    = (u16*)  alloc((size_t)2048 * 2048 * 2);        //  8.4 MB
  u16*   embs_bf  = (u16*)  alloc((size_t)T_ * B_ * EMB_ * 2);     //  2.6 MB
  float* embW     = (float*)alloc((size_t)(T_ + 1) * B_ * 2048 * 4); // 21.5 MB (slot 40 = dummy)
  float* meanE    = (float*)alloc((size_t)B_ * E_ * 4);
  u16*   h_bf     = (u16*)  alloc((size_t)B_ * D_ * 2);
  float* c_f      = (float*)alloc((size_t)B_ * D_ * 4);
  float* att2_f   = (float*)alloc((size_t)B_ * A_ * 4);
  float* gate_f   = (float*)alloc((size_t)B_ * E_ * 4);
  float* gates_f  = (float*)alloc((size_t)B_ * 2048 * 4);
  float* e_f      = (float*)alloc((size_t)B_ * P_ * 4);
  u16*   gctx_bf  = (u16*)  alloc((size_t)B_ * E_ * 2);
  float* bsum     = (float*)alloc(2048 * 4);
  if ((size_t)(w - (char*)d_ws) > ws_size) return;  // ws too small -> visible as absmax fail

  // ---- prolog ----
  k_cvt_bf16<<<25088, 256, 0, stream>>>(enc, enc_bf, (B_ * P_ * E_) / 4);
  k_mean<<<512, 256, 0, stream>>>(enc, meanE);
  // catW = [dec_att_W^T | f_beta_W^T | W_hh^T | fc_W^T], all K=512
  k_transpose_bf16<<<dim3(16, 16), 256, 0, stream>>>(dec_att_W, 512, catW, 512, 512, 512);
  k_transpose_bf16<<<dim3(16, 64), 256, 0, stream>>>(f_beta_W, 2048, catW + (size_t)512 * 512, 512, 2048, 512);
  k_transpose_bf16<<<dim3(16, 64), 256, 0, stream>>>(W_hh, 2048, catW + (size_t)2560 * 512, 512, 2048, 512);
  k_transpose_bf16<<<dim3(16, 313), 256, 0, stream>>>(fc_W, 10000, catW + (size_t)4608 * 512, 512, 10000, 512);
  hipMemsetAsync(catW + (size_t)NCAT * 512, 0, (size_t)(NCATP - NCAT) * 512 * 2, stream);
  k_transpose_bf16<<<dim3(64, 16), 256, 0, stream>>>(enc_att_W, 512, encattWT, 2048, 512, 2048);
  k_transpose_bf16<<<dim3(16, 64), 256, 0, stream>>>(W_ih, 2048, WihembT, 512, 2048, 512);
  k_transpose_bf16<<<dim3(64, 64), 256, 0, stream>>>(W_ih + (size_t)512 * 2048, 2048, Wih2T, 2048, 2048, 2048);
  k_bsum<<<8, 256, 0, stream>>>(b_ih, b_hh, bsum);
  k_init_hc<<<128, 256, 0, stream>>>(meanE, init_h_W, init_h_b, init_c_W, init_c_b, h_bf, c_f);
  k_emb<<<5120, 256, 0, stream>>>(captions, embedding, embs_bf);
  // att1[12544][512] = enc_bf @ enc_att_W + b   (stored bf16)
  k_gemm_bt<true><<<dim3(196, 8), 256, 0, stream>>>(enc_bf, encattWT, enc_att_b, att1_bf, 2048, 512);
  // embW[(t*64+b)][2048] = embs @ W_ih[:512] + (b_ih+b_hh)
  k_gemm_bt<false><<<dim3(40, 32), 256, 0, stream>>>(embs_bf, WihembT, bsum, embW, 512, 2048);

  // ---- main loop: t=0..39 steps; t=40 pass emits final preds only ----
  for (int t = 0; t <= T_; ++t) {
    int tm1 = t - 1;
    float* preds = preds_out + (size_t)(tm1 < 0 ? 0 : tm1) * V_;
    k_stepA<<<NCATP / 64, 256, 0, stream>>>(h_bf, catW, dec_att_b, f_beta_b, fc_b,
                                            embW + (size_t)t * B_ * 2048,
                                            att2_f, gate_f, gates_f, preds, tm1 >= 0 ? 1 : 0);
    if (t == T_) break;
    k_stepB<<<3136, 256, 0, stream>>>(att1_bf, att2_f, full_att_W, full_att_b, e_f);
    k_stepD<<<512, 256, 0, stream>>>(e_f, enc_bf, gate_f, alphas_out + (size_t)t * P_, gctx_bf);
    k_stepE1<<<256, 256, 0, stream>>>(gctx_bf, Wih2T, gates_f);
    k_stepE2<<<128, 256, 0, stream>>>(gates_f, c_f, h_bf);
  }
}

// Round 2
// 2558.155 us; speedup vs baseline: 1.1180x; 1.1180x over previous
//
#include <hip/hip_runtime.h>
#include <cstdint>
#include <cstddef>

// ---------------- problem constants ----------------
#define B_   64
#define P_   196
#define E_   2048
#define A_   512
#define D_   512
#define EMB_ 512
#define V_   10000
#define T_   40
// concatenated h-GEMM column space: [dec_att(512) | f_beta(2048) | W_hh(2048) | fc(10000)]
#define NCAT  14608
#define NCATP 14656   // padded to 229*64

typedef unsigned short u16;
typedef __attribute__((ext_vector_type(8))) short bf16x8;  // 8 bf16 = 4 VGPRs
typedef __attribute__((ext_vector_type(4))) float f32x4;

__device__ __forceinline__ f32x4 mfma_bf16(bf16x8 a, bf16x8 b, f32x4 c) {
  return __builtin_amdgcn_mfma_f32_16x16x32_bf16(a, b, c, 0, 0, 0);
}
__device__ __forceinline__ u16 f2b(float f) {            // RNE f32->bf16 (no NaN in data)
  unsigned u = __builtin_bit_cast(unsigned, f);
  u += 0x7fffu + ((u >> 16) & 1u);
  return (u16)(u >> 16);
}
__device__ __forceinline__ float b2f(u16 s) {
  unsigned u = ((unsigned)s) << 16;
  return __builtin_bit_cast(float, u);
}
__device__ __forceinline__ float sigf(float x) { return 1.0f / (1.0f + __expf(-x)); }

// async global->LDS, 16B per lane. LDS dst must be wave-uniform; lane l lands at dst + l*16B.
__device__ __forceinline__ void gl_lds16(const u16* gsrc, u16* ldst) {
  __builtin_amdgcn_global_load_lds(
      (const __attribute__((address_space(1))) unsigned int*)gsrc,
      (__attribute__((address_space(3))) unsigned int*)ldst,
      16, 0, 0);
}

// ---------------- prolog kernels ----------------
__global__ __launch_bounds__(256) void k_cvt_bf16(const float* __restrict__ s,
                                                  u16* __restrict__ d, int n4) {
  int i = blockIdx.x * 256 + threadIdx.x;
  if (i >= n4) return;
  float4 v = reinterpret_cast<const float4*>(s)[i];
  u16* o = d + (size_t)i * 4;
  o[0] = f2b(v.x); o[1] = f2b(v.y); o[2] = f2b(v.z); o[3] = f2b(v.w);
}

__global__ __launch_bounds__(256) void k_mean(const float* __restrict__ enc,
                                              u16* __restrict__ meanE_bf) {
  int i = blockIdx.x * 256 + threadIdx.x;   // 64*2048
  int b = i >> 11, e = i & 2047;
  const float* p = enc + (size_t)b * P_ * E_ + e;
  float s = 0.f;
  for (int pp = 0; pp < P_; ++pp) s += p[(size_t)pp * E_];
  meanE_bf[i] = f2b(s * (1.0f / (float)P_));
}

// dst[n*dstStride + k] = src[k*srcStride + n]  (fp32 -> bf16), LDS-tiled
__global__ __launch_bounds__(256) void k_transpose_bf16(
    const float* __restrict__ src, int srcStride,
    u16* __restrict__ dst, int dstStride, int N, int K) {
  __shared__ float t[32][33];
  int kt = blockIdx.x * 32, nt = blockIdx.y * 32;
  int tx = threadIdx.x & 31, ty = threadIdx.x >> 5;
  #pragma unroll
  for (int i = 0; i < 4; ++i) {
    int k = kt + ty + i * 8, n = nt + tx;
    t[ty + i * 8][tx] = (k < K && n < N) ? src[(size_t)k * srcStride + n] : 0.0f;
  }
  __syncthreads();
  #pragma unroll
  for (int i = 0; i < 4; ++i) {
    int n = nt + ty + i * 8, k = kt + tx;
    if (n < N && k < K) dst[(size_t)n * dstStride + k] = f2b(t[tx][ty + i * 8]);
  }
}

__global__ __launch_bounds__(256) void k_emb(const int* __restrict__ captions,
                                             const float* __restrict__ embedding,
                                             u16* __restrict__ embs) {
  int i = blockIdx.x * 256 + threadIdx.x;   // (T*B)*EMB, row m = t*64+b
  int m = i >> 9, k = i & 511;
  int t = m >> 6, b = m & 63;
  int cap = captions[b * T_ + t];
  embs[i] = f2b(embedding[(size_t)cap * EMB_ + k]);
}

__global__ __launch_bounds__(256) void k_bsum(const float* __restrict__ a,
                                              const float* __restrict__ b,
                                              float* __restrict__ o) {
  int i = blockIdx.x * 256 + threadIdx.x;   // 2048
  o[i] = a[i] + b[i];
}

__global__ __launch_bounds__(256) void k_catbias(const float* __restrict__ hb,
                                                 const float* __restrict__ cb,
                                                 float* __restrict__ o) {
  int i = blockIdx.x * 256 + threadIdx.x;   // 1024
  o[i] = (i < 512) ? hb[i] : cb[i - 512];
}

__global__ __launch_bounds__(256) void k_hc_pack(const float* __restrict__ initHC,
                                                 u16* __restrict__ h_bf,
                                                 float* __restrict__ c_f) {
  int i = blockIdx.x * 256 + threadIdx.x;   // 64*512
  int b = i >> 9, d = i & 511;
  h_bf[i] = f2b(initHC[b * 1024 + d]);
  c_f[i]  = initHC[b * 1024 + 512 + d];
}

// ---------------- small no-LDS MFMA GEMM (used once, M=64) ----------------
template <bool BF16OUT>
__global__ __launch_bounds__(256) void k_gemm_bt(
    const u16* __restrict__ Am, const u16* __restrict__ Bt,
    const float* __restrict__ bias, void* __restrict__ outp, int K, int N) {
  int m0 = blockIdx.x * 64, n0 = blockIdx.y * 64;
  int w = threadIdx.x >> 6, lane = threadIdx.x & 63;
  int lr = lane & 15, lg = lane >> 4;
  const u16* ap = Am + (size_t)(m0 + 16 * w + lr) * K + lg * 8;
  const u16* bp = Bt + (size_t)(n0 + lr) * K + lg * 8;
  f32x4 acc0 = {}, acc1 = {}, acc2 = {}, acc3 = {};
  for (int k = 0; k < K; k += 32) {
    bf16x8 a  = *reinterpret_cast<const bf16x8*>(ap + k);
    bf16x8 b0 = *reinterpret_cast<const bf16x8*>(bp + k);
    bf16x8 b1 = *reinterpret_cast<const bf16x8*>(bp + (size_t)16 * K + k);
    bf16x8 b2 = *reinterpret_cast<const bf16x8*>(bp + (size_t)32 * K + k);
    bf16x8 b3 = *reinterpret_cast<const bf16x8*>(bp + (size_t)48 * K + k);
    acc0 = mfma_bf16(a, b0, acc0);
    acc1 = mfma_bf16(a, b1, acc1);
    acc2 = mfma_bf16(a, b2, acc2);
    acc3 = mfma_bf16(a, b3, acc3);
  }
  int row = m0 + 16 * w + 4 * lg;
  f32x4 accs[4] = {acc0, acc1, acc2, acc3};
  #pragma unroll
  for (int ns = 0; ns < 4; ++ns) {
    int col = n0 + 16 * ns + lr;
    float bv = bias[col];
    #pragma unroll
    for (int r = 0; r < 4; ++r) {
      float v = accs[ns][r] + bv;
      if (BF16OUT) ((u16*)outp)[(size_t)(row + r) * N + col] = f2b(v);
      else         ((float*)outp)[(size_t)(row + r) * N + col] = v;
    }
  }
}

// ---------------- m97-style 128x128 LDS GEMM: out = A[M][K] @ Bt[N][K]^T + bias ----------------
// 256 thr = 4 waves in 2x2; BK=64; global_load_lds width16; single LDS buffer, 2 barriers/K-step.
// Requires M%128==0, N%128==0, K%64==0. grid = dim3(N/128, M/128) (n fast -> A-tile L2/L3 reuse).
template <bool BF16OUT>
__global__ __launch_bounds__(256) void k_gemm128(
    const u16* __restrict__ Am, const u16* __restrict__ Bt,
    const float* __restrict__ bias, void* __restrict__ outp, int K, int N) {
  __shared__ u16 lA[128 * 64];
  __shared__ u16 lB[128 * 64];
  int n0 = blockIdx.x * 128, m0 = blockIdx.y * 128;
  int w = threadIdx.x >> 6, lane = threadIdx.x & 63;
  int wr = w >> 1, wc = w & 1;
  int lr = lane & 15, lg = lane >> 4;
  // staging source coords for this lane (8 rows per 1KB chunk, 8 lanes per row)
  int srow = lane >> 3;            // 0..7 within chunk
  int scol = (lane & 7) * 8;       // element col 0..56
  f32x4 acc[4][4] = {};
  for (int kt = 0; kt < K; kt += 64) {
    #pragma unroll
    for (int q = 0; q < 4; ++q) {
      int r = (w * 4 + q) * 8 + srow;   // tile row 0..127
      gl_lds16(Am + (size_t)(m0 + r) * K + kt + scol, &lA[(w * 4 + q) * 512]);
      gl_lds16(Bt + (size_t)(n0 + r) * K + kt + scol, &lB[(w * 4 + q) * 512]);
    }
    __syncthreads();
    #pragma unroll
    for (int kk = 0; kk < 2; ++kk) {
      bf16x8 af[4], bf[4];
      #pragma unroll
      for (int m = 0; m < 4; ++m)
        af[m] = *reinterpret_cast<const bf16x8*>(&lA[(wr * 64 + m * 16 + lr) * 64 + kk * 32 + lg * 8]);
      #pragma unroll
      for (int n = 0; n < 4; ++n)
        bf[n] = *reinterpret_cast<const bf16x8*>(&lB[(wc * 64 + n * 16 + lr) * 64 + kk * 32 + lg * 8]);
      #pragma unroll
      for (int m = 0; m < 4; ++m)
        #pragma unroll
        for (int n = 0; n < 4; ++n)
          acc[m][n] = mfma_bf16(af[m], bf[n], acc[m][n]);
    }
    __syncthreads();
  }
  #pragma unroll
  for (int n = 0; n < 4; ++n) {
    int col = n0 + wc * 64 + n * 16 + lr;
    float bv = bias[col];
    #pragma unroll
    for (int m = 0; m < 4; ++m) {
      int row = m0 + wr * 64 + m * 16 + lg * 4;
      #pragma unroll
      for (int r = 0; r < 4; ++r) {
        float v = acc[m][n][r] + bv;
        if (BF16OUT) ((u16*)outp)[(size_t)(row + r) * N + col] = f2b(v);
        else         ((float*)outp)[(size_t)(row + r) * N + col] = v;
      }
    }
  }
}

// ---------------- per-step kernels ----------------
// A: all h-dependent GEMMs fused over concatenated N: att2 | sigmoid-gate | hWhh(+embW) | preds(prev)
__global__ __launch_bounds__(256) void k_stepA(
    const u16* __restrict__ h_bf, const u16* __restrict__ catW,
    const float* __restrict__ dec_b, const float* __restrict__ fbeta_b,
    const float* __restrict__ fc_b, const float* __restrict__ embW_t,
    float* __restrict__ att2, float* __restrict__ gate,
    float* __restrict__ gates, float* __restrict__ preds, int wp) {
  int n0 = blockIdx.x * 64;
  int w = threadIdx.x >> 6, lane = threadIdx.x & 63;
  int lr = lane & 15, lg = lane >> 4;
  const u16* ap = h_bf + (size_t)(16 * w + lr) * 512 + lg * 8;
  const u16* bp = catW + (size_t)(n0 + lr) * 512 + lg * 8;
  f32x4 acc0 = {}, acc1 = {}, acc2 = {}, acc3 = {};
  for (int k = 0; k < 512; k += 32) {
    bf16x8 a  = *reinterpret_cast<const bf16x8*>(ap + k);
    bf16x8 b0 = *reinterpret_cast<const bf16x8*>(bp + k);
    bf16x8 b1 = *reinterpret_cast<const bf16x8*>(bp + (size_t)16 * 512 + k);
    bf16x8 b2 = *reinterpret_cast<const bf16x8*>(bp + (size_t)32 * 512 + k);
    bf16x8 b3 = *reinterpret_cast<const bf16x8*>(bp + (size_t)48 * 512 + k);
    acc0 = mfma_bf16(a, b0, acc0);
    acc1 = mfma_bf16(a, b1, acc1);
    acc2 = mfma_bf16(a, b2, acc2);
    acc3 = mfma_bf16(a, b3, acc3);
  }
  int brow = 16 * w + 4 * lg;
  f32x4 accs[4] = {acc0, acc1, acc2, acc3};
  #pragma unroll
  for (int ns = 0; ns < 4; ++ns) {
    int n = n0 + 16 * ns + lr;
    #pragma unroll
    for (int r = 0; r < 4; ++r) {
      int b = brow + r;
      float v = accs[ns][r];
      if (n < 512) {
        att2[b * 512 + n] = v + dec_b[n];
      } else if (n < 2560) {
        int j = n - 512;
        gate[b * 2048 + j] = sigf(v + fbeta_b[j]);
      } else if (n < 4608) {
        int j = n - 2560;
        gates[b * 2048 + j] = v + embW_t[b * 2048 + j];  // embW already holds b_ih+b_hh
      } else if (n < 14608) {
        int j = n - 4608;
        if (wp) preds[(size_t)b * (T_ * V_) + j] = v + fc_b[j];
      }
    }
  }
}

// B: e[b,p] = relu(att1[b,p,:] + att2[b,:]) . full_att_W + full_att_b   (one wave per (b,p))
__global__ __launch_bounds__(256) void k_stepB(
    const u16* __restrict__ att1, const float* __restrict__ att2,
    const float* __restrict__ wf, const float* __restrict__ bf_,
    float* __restrict__ e) {
  int unit = blockIdx.x * 4 + (threadIdx.x >> 6);   // (b*196+p) in [0,12544)
  int lane = threadIdx.x & 63;
  int b = unit / 196;
  const u16*  a1  = att1 + (size_t)unit * 512 + lane * 8;
  const float* a2 = att2 + b * 512 + lane * 8;
  const float* wv = wf + lane * 8;
  float s = 0.f;
  #pragma unroll
  for (int j = 0; j < 8; ++j) {
    float x = b2f(a1[j]) + a2[j];
    s += fmaxf(x, 0.f) * wv[j];
  }
  #pragma unroll
  for (int off = 32; off > 0; off >>= 1) s += __shfl_xor(s, off);
  if (lane == 0) e[unit] = s + bf_[0];
}

// D: softmax(e) (redundant per block) + alphas out + context + gate*context -> bf16
__global__ __launch_bounds__(256) void k_stepD(
    const float* __restrict__ e, const u16* __restrict__ enc_bf,
    const float* __restrict__ gate, float* __restrict__ alphas,
    u16* __restrict__ gctx) {
  __shared__ float sal[P_];
  __shared__ float red[256];
  int b = blockIdx.x >> 3, ch = blockIdx.x & 7;
  int tid = threadIdx.x;
  float ev = (tid < P_) ? e[b * P_ + tid] : -1e30f;
  red[tid] = ev; __syncthreads();
  for (int s = 128; s > 0; s >>= 1) {
    if (tid < s) red[tid] = fmaxf(red[tid], red[tid + s]);
    __syncthreads();
  }
  float mx = red[0]; __syncthreads();
  float ex = (tid < P_) ? __expf(ev - mx) : 0.f;
  red[tid] = ex; __syncthreads();
  for (int s = 128; s > 0; s >>= 1) {
    if (tid < s) red[tid] += red[tid + s];
    __syncthreads();
  }
  float inv = 1.0f / red[0];
  if (tid < P_) {
    float al = ex * inv;
    sal[tid] = al;
    if (ch == 0) alphas[(size_t)b * (T_ * P_) + tid] = al;
  }
  __syncthreads();
  int eidx = ch * 256 + tid;
  const u16* ep = enc_bf + (size_t)b * P_ * E_ + eidx;
  float acc = 0.f;
  #pragma unroll 4
  for (int p = 0; p < P_; ++p) acc += sal[p] * b2f(ep[(size_t)p * E_]);
  gctx[b * E_ + eidx] = f2b(acc * gate[b * E_ + eidx]);
}

// E1: gates += (gate*context) @ W_ih[512:,:]   (split-K=8, atomicAdd)
__global__ __launch_bounds__(256) void k_stepE1(
    const u16* __restrict__ gctx, const u16* __restrict__ Wt,
    float* __restrict__ gates) {
  int n0 = (blockIdx.x & 31) * 64;
  int k0 = (blockIdx.x >> 5) * 256;
  int w = threadIdx.x >> 6, lane = threadIdx.x & 63;
  int lr = lane & 15, lg = lane >> 4;
  const u16* ap = gctx + (size_t)(16 * w + lr) * 2048 + lg * 8 + k0;
  const u16* bp = Wt + (size_t)(n0 + lr) * 2048 + lg * 8 + k0;
  f32x4 acc0 = {}, acc1 = {}, acc2 = {}, acc3 = {};
  for (int k = 0; k < 256; k += 32) {
    bf16x8 a  = *reinterpret_cast<const bf16x8*>(ap + k);
    bf16x8 b0 = *reinterpret_cast<const bf16x8*>(bp + k);
    bf16x8 b1 = *reinterpret_cast<const bf16x8*>(bp + (size_t)16 * 2048 + k);
    bf16x8 b2 = *reinterpret_cast<const bf16x8*>(bp + (size_t)32 * 2048 + k);
    bf16x8 b3 = *reinterpret_cast<const bf16x8*>(bp + (size_t)48 * 2048 + k);
    acc0 = mfma_bf16(a, b0, acc0);
    acc1 = mfma_bf16(a, b1, acc1);
    acc2 = mfma_bf16(a, b2, acc2);
    acc3 = mfma_bf16(a, b3, acc3);
  }
  int brow = 16 * w + 4 * lg;
  f32x4 accs[4] = {acc0, acc1, acc2, acc3};
  #pragma unroll
  for (int ns = 0; ns < 4; ++ns) {
    int n = n0 + 16 * ns + lr;
    #pragma unroll
    for (int r = 0; r < 4; ++r)
      atomicAdd(&gates[(brow + r) * 2048 + n], accs[ns][r]);
  }
}

// E2: LSTM cell elementwise
__global__ __launch_bounds__(256) void k_stepE2(
    const float* __restrict__ gates, float* __restrict__ c, u16* __restrict__ h_bf) {
  int i = blockIdx.x * 256 + threadIdx.x;   // 64*512
  int b = i >> 9, d = i & 511;
  const float* g = gates + (size_t)b * 2048;
  float gi = g[d], gf = g[d + 512], gg = g[d + 1024], go = g[d + 1536];
  float cn = sigf(gf) * c[i] + sigf(gi) * tanhf(gg);
  float hn = sigf(go) * tanhf(cn);
  c[i] = cn;
  h_bf[i] = f2b(hn);
}

// ---------------- host ----------------
extern "C" void kernel_launch(void* const* d_in, const int* in_sizes, int n_in,
                              void* d_out, int out_size, void* d_ws, size_t ws_size,
                              hipStream_t stream) {
  (void)in_sizes; (void)n_in; (void)out_size;
  const float* enc        = (const float*)d_in[0];
  const int*   captions   = (const int*)d_in[1];
  const float* enc_att_W  = (const float*)d_in[3];
  const float* enc_att_b  = (const float*)d_in[4];
  const float* dec_att_W  = (const float*)d_in[5];
  const float* dec_att_b  = (const float*)d_in[6];
  const float* full_att_W = (const float*)d_in[7];
  const float* full_att_b = (const float*)d_in[8];
  const float* embedding  = (const float*)d_in[9];
  const float* W_ih       = (const float*)d_in[10];
  const float* b_ih       = (const float*)d_in[11];
  const float* W_hh       = (const float*)d_in[12];
  const float* b_hh       = (const float*)d_in[13];
  const float* init_h_W   = (const float*)d_in[14];
  const float* init_h_b   = (const float*)d_in[15];
  const float* init_c_W   = (const float*)d_in[16];
  const float* init_c_b   = (const float*)d_in[17];
  const float* fc_W       = (const float*)d_in[18];
  const float* fc_b       = (const float*)d_in[19];
  const float* f_beta_W   = (const float*)d_in[20];
  const float* f_beta_b   = (const float*)d_in[21];

  float* preds_out  = (float*)d_out;                          // [64][40][10000]
  float* alphas_out = (float*)d_out + (size_t)B_ * T_ * V_;   // [64][40][196]

  char* w = (char*)d_ws;
  auto alloc = [&](size_t bytes) -> char* {
    char* p = w; w += (bytes + 255) & ~(size_t)255; return p;
  };
  u16*   enc_bf   = (u16*)  alloc((size_t)B_ * P_ * E_ * 2);       // 51.4 MB
  u16*   att1_bf  = (u16*)  alloc((size_t)B_ * P_ * A_ * 2);       // 12.8 MB
  u16*   catW     = (u16*)  alloc((size_t)NCATP * 512 * 2);        // 15.0 MB
  u16*   encattWT = (u16*)  alloc((size_t)A_ * E_ * 2);            //  2.1 MB
  u16*   WihembT  = (u16*)  alloc((size_t)2048 * 512 * 2);         //  2.1 MB
  u16*   Wih2T    = (u16*)  alloc((size_t)2048 * 2048 * 2);        //  8.4 MB
  u16*   embs_bf  = (u16*)  alloc((size_t)T_ * B_ * EMB_ * 2);     //  2.6 MB
  float* embW     = (float*)alloc((size_t)(T_ + 1) * B_ * 2048 * 4); // 21.5 MB (slot 40 = dummy)
  u16*   catInit  = (u16*)  alloc((size_t)1024 * 2048 * 2);        //  4.2 MB
  float* catInitB = (float*)alloc(1024 * 4);
  float* initHC   = (float*)alloc((size_t)B_ * 1024 * 4);
  u16*   meanE_bf = (u16*)  alloc((size_t)B_ * E_ * 2);
  u16*   h_bf     = (u16*)  alloc((size_t)B_ * D_ * 2);
  float* c_f      = (float*)alloc((size_t)B_ * D_ * 4);
  float* att2_f   = (float*)alloc((size_t)B_ * A_ * 4);
  float* gate_f   = (float*)alloc((size_t)B_ * E_ * 4);
  float* gates_f  = (float*)alloc((size_t)B_ * 2048 * 4);
  float* e_f      = (float*)alloc((size_t)B_ * P_ * 4);
  u16*   gctx_bf  = (u16*)  alloc((size_t)B_ * E_ * 2);
  float* bsum     = (float*)alloc(2048 * 4);
  if ((size_t)(w - (char*)d_ws) > ws_size) return;  // ws too small -> visible as absmax fail

  // ---- prolog ----
  k_cvt_bf16<<<25088, 256, 0, stream>>>(enc, enc_bf, (B_ * P_ * E_) / 4);
  k_mean<<<512, 256, 0, stream>>>(enc, meanE_bf);
  // catW = [dec_att_W^T | f_beta_W^T | W_hh^T | fc_W^T], all K=512
  k_transpose_bf16<<<dim3(16, 16), 256, 0, stream>>>(dec_att_W, 512, catW, 512, 512, 512);
  k_transpose_bf16<<<dim3(16, 64), 256, 0, stream>>>(f_beta_W, 2048, catW + (size_t)512 * 512, 512, 2048, 512);
  k_transpose_bf16<<<dim3(16, 64), 256, 0, stream>>>(W_hh, 2048, catW + (size_t)2560 * 512, 512, 2048, 512);
  k_transpose_bf16<<<dim3(16, 313), 256, 0, stream>>>(fc_W, 10000, catW + (size_t)4608 * 512, 512, 10000, 512);
  hipMemsetAsync(catW + (size_t)NCAT * 512, 0, (size_t)(NCATP - NCAT) * 512 * 2, stream);
  k_transpose_bf16<<<dim3(64, 16), 256, 0, stream>>>(enc_att_W, 512, encattWT, 2048, 512, 2048);
  k_transpose_bf16<<<dim3(16, 64), 256, 0, stream>>>(W_ih, 2048, WihembT, 512, 2048, 512);
  k_transpose_bf16<<<dim3(64, 64), 256, 0, stream>>>(W_ih + (size_t)512 * 2048, 2048, Wih2T, 2048, 2048, 2048);
  // init-state path: catInit = [init_h_W^T | init_c_W^T] (K=2048), then one MFMA GEMM
  k_transpose_bf16<<<dim3(64, 16), 256, 0, stream>>>(init_h_W, 512, catInit, 2048, 512, 2048);
  k_transpose_bf16<<<dim3(64, 16), 256, 0, stream>>>(init_c_W, 512, catInit + (size_t)512 * 2048, 2048, 512, 2048);
  k_catbias<<<4, 256, 0, stream>>>(init_h_b, init_c_b, catInitB);
  k_bsum<<<8, 256, 0, stream>>>(b_ih, b_hh, bsum);
  k_emb<<<5120, 256, 0, stream>>>(captions, embedding, embs_bf);
  k_gemm_bt<false><<<dim3(1, 16), 256, 0, stream>>>(meanE_bf, catInit, catInitB, initHC, 2048, 1024);
  k_hc_pack<<<128, 256, 0, stream>>>(initHC, h_bf, c_f);
  // att1[12544][512] = enc_bf @ enc_att_W + b   (stored bf16) — 128x128 LDS GEMM
  k_gemm128<true><<<dim3(4, 98), 256, 0, stream>>>(enc_bf, encattWT, enc_att_b, att1_bf, 2048, 512);
  // embW[(t*64+b)][2048] = embs @ W_ih[:512] + (b_ih+b_hh)
  k_gemm128<false><<<dim3(16, 20), 256, 0, stream>>>(embs_bf, WihembT, bsum, embW, 512, 2048);

  // ---- main loop: t=0..39 steps; t=40 pass emits final preds only ----
  for (int t = 0; t <= T_; ++t) {
    int tm1 = t - 1;
    float* preds = preds_out + (size_t)(tm1 < 0 ? 0 : tm1) * V_;
    k_stepA<<<NCATP / 64, 256, 0, stream>>>(h_bf, catW, dec_att_b, f_beta_b, fc_b,
                                            embW + (size_t)t * B_ * 2048,
                                            att2_f, gate_f, gates_f, preds, tm1 >= 0 ? 1 : 0);
    if (t == T_) break;
    k_stepB<<<3136, 256, 0, stream>>>(att1_bf, att2_f, full_att_W, full_att_b, e_f);
    k_stepD<<<512, 256, 0, stream>>>(e_f, enc_bf, gate_f, alphas_out + (size_t)t * P_, gctx_bf);
    k_stepE1<<<256, 256, 0, stream>>>(gctx_bf, Wih2T, gates_f);
    k_stepE2<<<128, 256, 0, stream>>>(gates_f, c_f, h_bf);
  }
}

// Round 3
// 2554.505 us; speedup vs baseline: 1.1196x; 1.0014x over previous
//
#include <hip/hip_runtime.h>
#include <cstdint>
#include <cstddef>

// ---------------- problem constants ----------------
#define B_   64
#define P_   196
#define E_   2048
#define A_   512
#define D_   512
#define EMB_ 512
#define V_   10000
#define T_   40
// concatenated h-GEMM column space (loop): [dec_att(512) | f_beta(2048) | W_hh(2048)]
#define NCAT  4608
// fc weight transposed, N padded to multiple of 128
#define VPAD  10112

typedef unsigned short u16;
typedef __attribute__((ext_vector_type(8))) short bf16x8;  // 8 bf16 = 4 VGPRs
typedef __attribute__((ext_vector_type(4))) float f32x4;

__device__ __forceinline__ f32x4 mfma_bf16(bf16x8 a, bf16x8 b, f32x4 c) {
  return __builtin_amdgcn_mfma_f32_16x16x32_bf16(a, b, c, 0, 0, 0);
}
__device__ __forceinline__ u16 f2b(float f) {            // RNE f32->bf16 (no NaN in data)
  unsigned u = __builtin_bit_cast(unsigned, f);
  u += 0x7fffu + ((u >> 16) & 1u);
  return (u16)(u >> 16);
}
__device__ __forceinline__ float b2f(u16 s) {
  unsigned u = ((unsigned)s) << 16;
  return __builtin_bit_cast(float, u);
}
__device__ __forceinline__ float sigf(float x) { return 1.0f / (1.0f + __expf(-x)); }

// async global->LDS, 16B per lane. LDS dst must be wave-uniform; lane l lands at dst + l*16B.
__device__ __forceinline__ void gl_lds16(const u16* gsrc, u16* ldst) {
  __builtin_amdgcn_global_load_lds(
      (const __attribute__((address_space(1))) unsigned int*)gsrc,
      (__attribute__((address_space(3))) unsigned int*)ldst,
      16, 0, 0);
}

// ---------------- prolog kernels ----------------
__global__ __launch_bounds__(256) void k_cvt_bf16(const float* __restrict__ s,
                                                  u16* __restrict__ d, int n4) {
  int i = blockIdx.x * 256 + threadIdx.x;
  if (i >= n4) return;
  float4 v = reinterpret_cast<const float4*>(s)[i];
  u16* o = d + (size_t)i * 4;
  o[0] = f2b(v.x); o[1] = f2b(v.y); o[2] = f2b(v.z); o[3] = f2b(v.w);
}

__global__ __launch_bounds__(256) void k_mean(const float* __restrict__ enc,
                                              u16* __restrict__ meanE_bf) {
  int i = blockIdx.x * 256 + threadIdx.x;   // 64*2048
  int b = i >> 11, e = i & 2047;
  const float* p = enc + (size_t)b * P_ * E_ + e;
  float s = 0.f;
  for (int pp = 0; pp < P_; ++pp) s += p[(size_t)pp * E_];
  meanE_bf[i] = f2b(s * (1.0f / (float)P_));
}

// dst[n*dstStride + k] = src[k*srcStride + n]  (fp32 -> bf16), LDS-tiled
__global__ __launch_bounds__(256) void k_transpose_bf16(
    const float* __restrict__ src, int srcStride,
    u16* __restrict__ dst, int dstStride, int N, int K) {
  __shared__ float t[32][33];
  int kt = blockIdx.x * 32, nt = blockIdx.y * 32;
  int tx = threadIdx.x & 31, ty = threadIdx.x >> 5;
  #pragma unroll
  for (int i = 0; i < 4; ++i) {
    int k = kt + ty + i * 8, n = nt + tx;
    t[ty + i * 8][tx] = (k < K && n < N) ? src[(size_t)k * srcStride + n] : 0.0f;
  }
  __syncthreads();
  #pragma unroll
  for (int i = 0; i < 4; ++i) {
    int n = nt + ty + i * 8, k = kt + tx;
    if (n < N && k < K) dst[(size_t)n * dstStride + k] = f2b(t[tx][ty + i * 8]);
  }
}

__global__ __launch_bounds__(256) void k_emb(const int* __restrict__ captions,
                                             const float* __restrict__ embedding,
                                             u16* __restrict__ embs) {
  int i = blockIdx.x * 256 + threadIdx.x;   // (T*B)*EMB, row m = t*64+b
  int m = i >> 9, k = i & 511;
  int t = m >> 6, b = m & 63;
  int cap = captions[b * T_ + t];
  embs[i] = f2b(embedding[(size_t)cap * EMB_ + k]);
}

__global__ __launch_bounds__(256) void k_bsum(const float* __restrict__ a,
                                              const float* __restrict__ b,
                                              float* __restrict__ o) {
  int i = blockIdx.x * 256 + threadIdx.x;   // 2048
  o[i] = a[i] + b[i];
}

__global__ __launch_bounds__(256) void k_catbias(const float* __restrict__ hb,
                                                 const float* __restrict__ cb,
                                                 float* __restrict__ o) {
  int i = blockIdx.x * 256 + threadIdx.x;   // 1024
  o[i] = (i < 512) ? hb[i] : cb[i - 512];
}

__global__ __launch_bounds__(256) void k_hc_pack(const float* __restrict__ initHC,
                                                 u16* __restrict__ h0_bf,
                                                 float* __restrict__ c_f) {
  int i = blockIdx.x * 256 + threadIdx.x;   // 64*512
  int b = i >> 9, d = i & 511;
  h0_bf[i] = f2b(initHC[b * 1024 + d]);
  c_f[i]  = initHC[b * 1024 + 512 + d];
}

// ---------------- small no-LDS MFMA GEMM (used once, M=64) ----------------
template <bool BF16OUT>
__global__ __launch_bounds__(256) void k_gemm_bt(
    const u16* __restrict__ Am, const u16* __restrict__ Bt,
    const float* __restrict__ bias, void* __restrict__ outp, int K, int N) {
  int m0 = blockIdx.x * 64, n0 = blockIdx.y * 64;
  int w = threadIdx.x >> 6, lane = threadIdx.x & 63;
  int lr = lane & 15, lg = lane >> 4;
  const u16* ap = Am + (size_t)(m0 + 16 * w + lr) * K + lg * 8;
  const u16* bp = Bt + (size_t)(n0 + lr) * K + lg * 8;
  f32x4 acc0 = {}, acc1 = {}, acc2 = {}, acc3 = {};
  for (int k = 0; k < K; k += 32) {
    bf16x8 a  = *reinterpret_cast<const bf16x8*>(ap + k);
    bf16x8 b0 = *reinterpret_cast<const bf16x8*>(bp + k);
    bf16x8 b1 = *reinterpret_cast<const bf16x8*>(bp + (size_t)16 * K + k);
    bf16x8 b2 = *reinterpret_cast<const bf16x8*>(bp + (size_t)32 * K + k);
    bf16x8 b3 = *reinterpret_cast<const bf16x8*>(bp + (size_t)48 * K + k);
    acc0 = mfma_bf16(a, b0, acc0);
    acc1 = mfma_bf16(a, b1, acc1);
    acc2 = mfma_bf16(a, b2, acc2);
    acc3 = mfma_bf16(a, b3, acc3);
  }
  int row = m0 + 16 * w + 4 * lg;
  f32x4 accs[4] = {acc0, acc1, acc2, acc3};
  #pragma unroll
  for (int ns = 0; ns < 4; ++ns) {
    int col = n0 + 16 * ns + lr;
    float bv = bias[col];
    #pragma unroll
    for (int r = 0; r < 4; ++r) {
      float v = accs[ns][r] + bv;
      if (BF16OUT) ((u16*)outp)[(size_t)(row + r) * N + col] = f2b(v);
      else         ((float*)outp)[(size_t)(row + r) * N + col] = v;
    }
  }
}

// ---------------- m97-style 128x128 LDS GEMM: out = A[M][K] @ Bt[N][K]^T + bias ----------------
// 256 thr = 4 waves in 2x2; BK=64; global_load_lds width16; single LDS buffer, 2 barriers/K-step.
// Requires M%128==0, N%128==0, K%64==0. grid = dim3(N/128, M/128).
template <bool BF16OUT>
__global__ __launch_bounds__(256) void k_gemm128(
    const u16* __restrict__ Am, const u16* __restrict__ Bt,
    const float* __restrict__ bias, void* __restrict__ outp, int K, int N) {
  __shared__ u16 lA[128 * 64];
  __shared__ u16 lB[128 * 64];
  int n0 = blockIdx.x * 128, m0 = blockIdx.y * 128;
  int w = threadIdx.x >> 6, lane = threadIdx.x & 63;
  int wr = w >> 1, wc = w & 1;
  int lr = lane & 15, lg = lane >> 4;
  int srow = lane >> 3;            // 0..7 within chunk
  int scol = (lane & 7) * 8;       // element col 0..56
  f32x4 acc[4][4] = {};
  for (int kt = 0; kt < K; kt += 64) {
    #pragma unroll
    for (int q = 0; q < 4; ++q) {
      int r = (w * 4 + q) * 8 + srow;   // tile row 0..127
      gl_lds16(Am + (size_t)(m0 + r) * K + kt + scol, &lA[(w * 4 + q) * 512]);
      gl_lds16(Bt + (size_t)(n0 + r) * K + kt + scol, &lB[(w * 4 + q) * 512]);
    }
    __syncthreads();
    #pragma unroll
    for (int kk = 0; kk < 2; ++kk) {
      bf16x8 af[4], bf[4];
      #pragma unroll
      for (int m = 0; m < 4; ++m)
        af[m] = *reinterpret_cast<const bf16x8*>(&lA[(wr * 64 + m * 16 + lr) * 64 + kk * 32 + lg * 8]);
      #pragma unroll
      for (int n = 0; n < 4; ++n)
        bf[n] = *reinterpret_cast<const bf16x8*>(&lB[(wc * 64 + n * 16 + lr) * 64 + kk * 32 + lg * 8]);
      #pragma unroll
      for (int m = 0; m < 4; ++m)
        #pragma unroll
        for (int n = 0; n < 4; ++n)
          acc[m][n] = mfma_bf16(af[m], bf[n], acc[m][n]);
    }
    __syncthreads();
  }
  #pragma unroll
  for (int n = 0; n < 4; ++n) {
    int col = n0 + wc * 64 + n * 16 + lr;
    float bv = bias[col];
    #pragma unroll
    for (int m = 0; m < 4; ++m) {
      int row = m0 + wr * 64 + m * 16 + lg * 4;
      #pragma unroll
      for (int r = 0; r < 4; ++r) {
        float v = acc[m][n][r] + bv;
        if (BF16OUT) ((u16*)outp)[(size_t)(row + r) * N + col] = f2b(v);
        else         ((float*)outp)[(size_t)(row + r) * N + col] = v;
      }
    }
  }
}

// ---- batched fc GEMM: preds[b][t][col] = Hall1[t*64+b][:] @ fcWT[col][:] + fc_b[col] ----
// A rows r = t*64+b (r < 2560), Bt = fcWT [VPAD][512] (rows >= V_ zero), col guard at V_.
__global__ __launch_bounds__(256) void k_gemm_fc(
    const u16* __restrict__ Hall1, const u16* __restrict__ fcWT,
    const float* __restrict__ fc_b, float* __restrict__ preds_out) {
  __shared__ u16 lA[128 * 64];
  __shared__ u16 lB[128 * 64];
  int n0 = blockIdx.x * 128, m0 = blockIdx.y * 128;
  int w = threadIdx.x >> 6, lane = threadIdx.x & 63;
  int wr = w >> 1, wc = w & 1;
  int lr = lane & 15, lg = lane >> 4;
  int srow = lane >> 3;
  int scol = (lane & 7) * 8;
  f32x4 acc[4][4] = {};
  for (int kt = 0; kt < 512; kt += 64) {
    #pragma unroll
    for (int q = 0; q < 4; ++q) {
      int r = (w * 4 + q) * 8 + srow;
      gl_lds16(Hall1 + (size_t)(m0 + r) * 512 + kt + scol, &lA[(w * 4 + q) * 512]);
      gl_lds16(fcWT + (size_t)(n0 + r) * 512 + kt + scol, &lB[(w * 4 + q) * 512]);
    }
    __syncthreads();
    #pragma unroll
    for (int kk = 0; kk < 2; ++kk) {
      bf16x8 af[4], bf[4];
      #pragma unroll
      for (int m = 0; m < 4; ++m)
        af[m] = *reinterpret_cast<const bf16x8*>(&lA[(wr * 64 + m * 16 + lr) * 64 + kk * 32 + lg * 8]);
      #pragma unroll
      for (int n = 0; n < 4; ++n)
        bf[n] = *reinterpret_cast<const bf16x8*>(&lB[(wc * 64 + n * 16 + lr) * 64 + kk * 32 + lg * 8]);
      #pragma unroll
      for (int m = 0; m < 4; ++m)
        #pragma unroll
        for (int n = 0; n < 4; ++n)
          acc[m][n] = mfma_bf16(af[m], bf[n], acc[m][n]);
    }
    __syncthreads();
  }
  #pragma unroll
  for (int n = 0; n < 4; ++n) {
    int col = n0 + wc * 64 + n * 16 + lr;
    if (col >= V_) continue;
    float bv = fc_b[col];
    #pragma unroll
    for (int m = 0; m < 4; ++m) {
      int row = m0 + wr * 64 + m * 16 + lg * 4;
      #pragma unroll
      for (int r = 0; r < 4; ++r) {
        int rr = row + r;                 // = t*64 + b
        int t = rr >> 6, b = rr & 63;
        preds_out[((size_t)b * T_ + t) * V_ + col] = acc[m][n][r] + bv;
      }
    }
  }
}

// ---------------- per-step kernels ----------------
// A: h-dependent GEMMs fused over concatenated N: att2 | sigmoid-gate | hWhh(+embW)
__global__ __launch_bounds__(256) void k_stepA(
    const u16* __restrict__ h_bf, const u16* __restrict__ catW,
    const float* __restrict__ dec_b, const float* __restrict__ fbeta_b,
    const float* __restrict__ embW_t,
    float* __restrict__ att2, float* __restrict__ gate,
    float* __restrict__ gates) {
  int n0 = blockIdx.x * 64;
  int w = threadIdx.x >> 6, lane = threadIdx.x & 63;
  int lr = lane & 15, lg = lane >> 4;
  const u16* ap = h_bf + (size_t)(16 * w + lr) * 512 + lg * 8;
  const u16* bp = catW + (size_t)(n0 + lr) * 512 + lg * 8;
  f32x4 acc0 = {}, acc1 = {}, acc2 = {}, acc3 = {};
  for (int k = 0; k < 512; k += 32) {
    bf16x8 a  = *reinterpret_cast<const bf16x8*>(ap + k);
    bf16x8 b0 = *reinterpret_cast<const bf16x8*>(bp + k);
    bf16x8 b1 = *reinterpret_cast<const bf16x8*>(bp + (size_t)16 * 512 + k);
    bf16x8 b2 = *reinterpret_cast<const bf16x8*>(bp + (size_t)32 * 512 + k);
    bf16x8 b3 = *reinterpret_cast<const bf16x8*>(bp + (size_t)48 * 512 + k);
    acc0 = mfma_bf16(a, b0, acc0);
    acc1 = mfma_bf16(a, b1, acc1);
    acc2 = mfma_bf16(a, b2, acc2);
    acc3 = mfma_bf16(a, b3, acc3);
  }
  int brow = 16 * w + 4 * lg;
  f32x4 accs[4] = {acc0, acc1, acc2, acc3};
  #pragma unroll
  for (int ns = 0; ns < 4; ++ns) {
    int n = n0 + 16 * ns + lr;
    #pragma unroll
    for (int r = 0; r < 4; ++r) {
      int b = brow + r;
      float v = accs[ns][r];
      if (n < 512) {
        att2[b * 512 + n] = v + dec_b[n];
      } else if (n < 2560) {
        int j = n - 512;
        gate[b * 2048 + j] = sigf(v + fbeta_b[j]);
      } else {
        int j = n - 2560;
        gates[b * 2048 + j] = v + embW_t[b * 2048 + j];  // embW already holds b_ih+b_hh
      }
    }
  }
}

// B: e[b,p] = relu(att1[b,p,:] + att2[b,:]) . full_att_W + full_att_b   (one wave per (b,p))
__global__ __launch_bounds__(256) void k_stepB(
    const u16* __restrict__ att1, const float* __restrict__ att2,
    const float* __restrict__ wf, const float* __restrict__ bf_,
    float* __restrict__ e) {
  int unit = blockIdx.x * 4 + (threadIdx.x >> 6);   // (b*196+p) in [0,12544)
  int lane = threadIdx.x & 63;
  int b = unit / 196;
  const u16*  a1  = att1 + (size_t)unit * 512 + lane * 8;
  const float* a2 = att2 + b * 512 + lane * 8;
  const float* wv = wf + lane * 8;
  float s = 0.f;
  #pragma unroll
  for (int j = 0; j < 8; ++j) {
    float x = b2f(a1[j]) + a2[j];
    s += fmaxf(x, 0.f) * wv[j];
  }
  #pragma unroll
  for (int off = 32; off > 0; off >>= 1) s += __shfl_xor(s, off);
  if (lane == 0) e[unit] = s + bf_[0];
}

// D: softmax(e) (redundant per block) + alphas out + context + gate*context -> bf16
__global__ __launch_bounds__(256) void k_stepD(
    const float* __restrict__ e, const u16* __restrict__ enc_bf,
    const float* __restrict__ gate, float* __restrict__ alphas,
    u16* __restrict__ gctx) {
  __shared__ float sal[P_];
  __shared__ float red[256];
  int b = blockIdx.x >> 3, ch = blockIdx.x & 7;
  int tid = threadIdx.x;
  float ev = (tid < P_) ? e[b * P_ + tid] : -1e30f;
  red[tid] = ev; __syncthreads();
  for (int s = 128; s > 0; s >>= 1) {
    if (tid < s) red[tid] = fmaxf(red[tid], red[tid + s]);
    __syncthreads();
  }
  float mx = red[0]; __syncthreads();
  float ex = (tid < P_) ? __expf(ev - mx) : 0.f;
  red[tid] = ex; __syncthreads();
  for (int s = 128; s > 0; s >>= 1) {
    if (tid < s) red[tid] += red[tid + s];
    __syncthreads();
  }
  float inv = 1.0f / red[0];
  if (tid < P_) {
    float al = ex * inv;
    sal[tid] = al;
    if (ch == 0) alphas[(size_t)b * (T_ * P_) + tid] = al;
  }
  __syncthreads();
  int eidx = ch * 256 + tid;
  const u16* ep = enc_bf + (size_t)b * P_ * E_ + eidx;
  float acc = 0.f;
  #pragma unroll 4
  for (int p = 0; p < P_; ++p) acc += sal[p] * b2f(ep[(size_t)p * E_]);
  gctx[b * E_ + eidx] = f2b(acc * gate[b * E_ + eidx]);
}

// E1: gates += (gate*context) @ W_ih[512:,:]   (split-K=8, atomicAdd)
__global__ __launch_bounds__(256) void k_stepE1(
    const u16* __restrict__ gctx, const u16* __restrict__ Wt,
    float* __restrict__ gates) {
  int n0 = (blockIdx.x & 31) * 64;
  int k0 = (blockIdx.x >> 5) * 256;
  int w = threadIdx.x >> 6, lane = threadIdx.x & 63;
  int lr = lane & 15, lg = lane >> 4;
  const u16* ap = gctx + (size_t)(16 * w + lr) * 2048 + lg * 8 + k0;
  const u16* bp = Wt + (size_t)(n0 + lr) * 2048 + lg * 8 + k0;
  f32x4 acc0 = {}, acc1 = {}, acc2 = {}, acc3 = {};
  for (int k = 0; k < 256; k += 32) {
    bf16x8 a  = *reinterpret_cast<const bf16x8*>(ap + k);
    bf16x8 b0 = *reinterpret_cast<const bf16x8*>(bp + k);
    bf16x8 b1 = *reinterpret_cast<const bf16x8*>(bp + (size_t)16 * 2048 + k);
    bf16x8 b2 = *reinterpret_cast<const bf16x8*>(bp + (size_t)32 * 2048 + k);
    bf16x8 b3 = *reinterpret_cast<const bf16x8*>(bp + (size_t)48 * 2048 + k);
    acc0 = mfma_bf16(a, b0, acc0);
    acc1 = mfma_bf16(a, b1, acc1);
    acc2 = mfma_bf16(a, b2, acc2);
    acc3 = mfma_bf16(a, b3, acc3);
  }
  int brow = 16 * w + 4 * lg;
  f32x4 accs[4] = {acc0, acc1, acc2, acc3};
  #pragma unroll
  for (int ns = 0; ns < 4; ++ns) {
    int n = n0 + 16 * ns + lr;
    #pragma unroll
    for (int r = 0; r < 4; ++r)
      atomicAdd(&gates[(brow + r) * 2048 + n], accs[ns][r]);
  }
}

// E2: LSTM cell elementwise; writes h (bf16) into Hall slice t+1
__global__ __launch_bounds__(256) void k_stepE2(
    const float* __restrict__ gates, float* __restrict__ c, u16* __restrict__ h_out) {
  int i = blockIdx.x * 256 + threadIdx.x;   // 64*512
  int b = i >> 9, d = i & 511;
  const float* g = gates + (size_t)b * 2048;
  float gi = g[d], gf = g[d + 512], gg = g[d + 1024], go = g[d + 1536];
  float cn = sigf(gf) * c[i] + sigf(gi) * tanhf(gg);
  float hn = sigf(go) * tanhf(cn);
  c[i] = cn;
  h_out[i] = f2b(hn);
}

// ---------------- host ----------------
extern "C" void kernel_launch(void* const* d_in, const int* in_sizes, int n_in,
                              void* d_out, int out_size, void* d_ws, size_t ws_size,
                              hipStream_t stream) {
  (void)in_sizes; (void)n_in; (void)out_size;
  const float* enc        = (const float*)d_in[0];
  const int*   captions   = (const int*)d_in[1];
  const float* enc_att_W  = (const float*)d_in[3];
  const float* enc_att_b  = (const float*)d_in[4];
  const float* dec_att_W  = (const float*)d_in[5];
  const float* dec_att_b  = (const float*)d_in[6];
  const float* full_att_W = (const float*)d_in[7];
  const float* full_att_b = (const float*)d_in[8];
  const float* embedding  = (const float*)d_in[9];
  const float* W_ih       = (const float*)d_in[10];
  const float* b_ih       = (const float*)d_in[11];
  const float* W_hh       = (const float*)d_in[12];
  const float* b_hh       = (const float*)d_in[13];
  const float* init_h_W   = (const float*)d_in[14];
  const float* init_h_b   = (const float*)d_in[15];
  const float* init_c_W   = (const float*)d_in[16];
  const float* init_c_b   = (const float*)d_in[17];
  const float* fc_W       = (const float*)d_in[18];
  const float* fc_b       = (const float*)d_in[19];
  const float* f_beta_W   = (const float*)d_in[20];
  const float* f_beta_b   = (const float*)d_in[21];

  float* preds_out  = (float*)d_out;                          // [64][40][10000]
  float* alphas_out = (float*)d_out + (size_t)B_ * T_ * V_;   // [64][40][196]

  char* w = (char*)d_ws;
  auto alloc = [&](size_t bytes) -> char* {
    char* p = w; w += (bytes + 255) & ~(size_t)255; return p;
  };
  u16*   enc_bf   = (u16*)  alloc((size_t)B_ * P_ * E_ * 2);       // 51.4 MB
  u16*   att1_bf  = (u16*)  alloc((size_t)B_ * P_ * A_ * 2);       // 12.8 MB
  u16*   catW     = (u16*)  alloc((size_t)NCAT * 512 * 2);         //  4.7 MB
  u16*   fcWT     = (u16*)  alloc((size_t)VPAD * 512 * 2);         // 10.4 MB
  u16*   encattWT = (u16*)  alloc((size_t)A_ * E_ * 2);            //  2.1 MB
  u16*   WihembT  = (u16*)  alloc((size_t)2048 * 512 * 2);         //  2.1 MB
  u16*   Wih2T    = (u16*)  alloc((size_t)2048 * 2048 * 2);        //  8.4 MB
  u16*   embs_bf  = (u16*)  alloc((size_t)T_ * B_ * EMB_ * 2);     //  2.6 MB
  float* embW     = (float*)alloc((size_t)T_ * B_ * 2048 * 4);     // 21.0 MB
  u16*   Hall     = (u16*)  alloc((size_t)(T_ + 1) * B_ * D_ * 2); //  2.7 MB (slice 0 = init h)
  u16*   catInit  = (u16*)  alloc((size_t)1024 * 2048 * 2);        //  4.2 MB
  float* catInitB = (float*)alloc(1024 * 4);
  float* initHC   = (float*)alloc((size_t)B_ * 1024 * 4);
  u16*   meanE_bf = (u16*)  alloc((size_t)B_ * E_ * 2);
  float* c_f      = (float*)alloc((size_t)B_ * D_ * 4);
  float* att2_f   = (float*)alloc((size_t)B_ * A_ * 4);
  float* gate_f   = (float*)alloc((size_t)B_ * E_ * 4);
  float* gates_f  = (float*)alloc((size_t)B_ * 2048 * 4);
  float* e_f      = (float*)alloc((size_t)B_ * P_ * 4);
  u16*   gctx_bf  = (u16*)  alloc((size_t)B_ * E_ * 2);
  float* bsum     = (float*)alloc(2048 * 4);
  if ((size_t)(w - (char*)d_ws) > ws_size) return;  // ws too small -> visible as absmax fail

  // ---- prolog ----
  k_cvt_bf16<<<25088, 256, 0, stream>>>(enc, enc_bf, (B_ * P_ * E_) / 4);
  k_mean<<<512, 256, 0, stream>>>(enc, meanE_bf);
  // catW = [dec_att_W^T | f_beta_W^T | W_hh^T], all K=512
  k_transpose_bf16<<<dim3(16, 16), 256, 0, stream>>>(dec_att_W, 512, catW, 512, 512, 512);
  k_transpose_bf16<<<dim3(16, 64), 256, 0, stream>>>(f_beta_W, 2048, catW + (size_t)512 * 512, 512, 2048, 512);
  k_transpose_bf16<<<dim3(16, 64), 256, 0, stream>>>(W_hh, 2048, catW + (size_t)2560 * 512, 512, 2048, 512);
  // fcWT rows [0,10000) = fc_W^T; pad rows zeroed
  hipMemsetAsync(fcWT + (size_t)V_ * 512, 0, (size_t)(VPAD - V_) * 512 * 2, stream);
  k_transpose_bf16<<<dim3(16, 313), 256, 0, stream>>>(fc_W, 10000, fcWT, 512, 10000, 512);
  k_transpose_bf16<<<dim3(64, 16), 256, 0, stream>>>(enc_att_W, 512, encattWT, 2048, 512, 2048);
  k_transpose_bf16<<<dim3(16, 64), 256, 0, stream>>>(W_ih, 2048, WihembT, 512, 2048, 512);
  k_transpose_bf16<<<dim3(64, 64), 256, 0, stream>>>(W_ih + (size_t)512 * 2048, 2048, Wih2T, 2048, 2048, 2048);
  // init-state path: catInit = [init_h_W^T | init_c_W^T] (K=2048), then one MFMA GEMM
  k_transpose_bf16<<<dim3(64, 16), 256, 0, stream>>>(init_h_W, 512, catInit, 2048, 512, 2048);
  k_transpose_bf16<<<dim3(64, 16), 256, 0, stream>>>(init_c_W, 512, catInit + (size_t)512 * 2048, 2048, 512, 2048);
  k_catbias<<<4, 256, 0, stream>>>(init_h_b, init_c_b, catInitB);
  k_bsum<<<8, 256, 0, stream>>>(b_ih, b_hh, bsum);
  k_emb<<<5120, 256, 0, stream>>>(captions, embedding, embs_bf);
  k_gemm_bt<false><<<dim3(1, 16), 256, 0, stream>>>(meanE_bf, catInit, catInitB, initHC, 2048, 1024);
  k_hc_pack<<<128, 256, 0, stream>>>(initHC, Hall, c_f);
  // att1[12544][512] = enc_bf @ enc_att_W + b   (stored bf16) — 128x128 LDS GEMM
  k_gemm128<true><<<dim3(4, 98), 256, 0, stream>>>(enc_bf, encattWT, enc_att_b, att1_bf, 2048, 512);
  // embW[(t*64+b)][2048] = embs @ W_ih[:512] + (b_ih+b_hh)
  k_gemm128<false><<<dim3(16, 20), 256, 0, stream>>>(embs_bf, WihembT, bsum, embW, 512, 2048);

  // ---- main loop ----
  for (int t = 0; t < T_; ++t) {
    const u16* h_prev = Hall + (size_t)t * B_ * D_;
    u16* h_next = Hall + (size_t)(t + 1) * B_ * D_;
    k_stepA<<<NCAT / 64, 256, 0, stream>>>(h_prev, catW, dec_att_b, f_beta_b,
                                           embW + (size_t)t * B_ * 2048,
                                           att2_f, gate_f, gates_f);
    k_stepB<<<3136, 256, 0, stream>>>(att1_bf, att2_f, full_att_W, full_att_b, e_f);
    k_stepD<<<512, 256, 0, stream>>>(e_f, enc_bf, gate_f, alphas_out + (size_t)t * P_, gctx_bf);
    k_stepE1<<<256, 256, 0, stream>>>(gctx_bf, Wih2T, gates_f);
    k_stepE2<<<128, 256, 0, stream>>>(gates_f, c_f, h_next);
  }
  // ---- batched fc: preds for all t ----
  k_gemm_fc<<<dim3(VPAD / 128, (T_ * B_) / 128), 256, 0, stream>>>(
      Hall + (size_t)B_ * D_, fcWT, fc_b, preds_out);
}